// Round 15
// baseline (1542.453 us; speedup 1.0000x reference)
//
#include <hip/hip_runtime.h>
#include <stdint.h>

#define NN 50000
#define NE 800000
#define NR 8
#define EMBD 512
#define PROJD 256
#define HIDD 256
#define OUTD 200
#define NSEG (NN * NR)
#define CSR_CAP 1536
#define NBK 784  // ceil(50000/64) = 782, padded

typedef _Float16 half8 __attribute__((ext_vector_type(8)));
typedef _Float16 half4 __attribute__((ext_vector_type(4)));
typedef float f32x4 __attribute__((ext_vector_type(4)));

// ---------------- async global->LDS ----------------
__device__ __forceinline__ void gload16(const void* g, void* l) {
    __builtin_amdgcn_global_load_lds(
        reinterpret_cast<const __attribute__((address_space(1))) uint32_t*>(
            reinterpret_cast<uintptr_t>(g)),
        reinterpret_cast<__attribute__((address_space(3))) uint32_t*>(
            reinterpret_cast<uintptr_t>(l)),
        16, 0, 0);
}

// ---------------- CSR build ----------------

__global__ void count_edges(const int* __restrict__ dst, const int* __restrict__ rel,
                            int* __restrict__ cnt, int E) {
    int e = blockIdx.x * 256 + threadIdx.x;
    if (e >= E) return;
    atomicAdd(&cnt[dst[e] * NR + rel[e]], 1);
}

__global__ __launch_bounds__(512) void scan1(const int* __restrict__ cnt, int* __restrict__ offs,
                                             int* __restrict__ bsums, int n) {
    __shared__ int sm[512];
    int tid = threadIdx.x;
    int g = blockIdx.x * 512 + tid;
    int v = (g < n) ? cnt[g] : 0;
    sm[tid] = v;
    __syncthreads();
    for (int o = 1; o < 512; o <<= 1) {
        int t = (tid >= o) ? sm[tid - o] : 0;
        __syncthreads();
        sm[tid] += t;
        __syncthreads();
    }
    if (g < n) offs[g] = sm[tid] - v;
    if (tid == 511) bsums[blockIdx.x] = sm[511];
}

__global__ __launch_bounds__(1024) void scan2(const int* __restrict__ bsums, int* __restrict__ bpref, int nb) {
    __shared__ int sm[1024];
    int tid = threadIdx.x;
    int v = (tid < nb) ? bsums[tid] : 0;
    sm[tid] = v;
    __syncthreads();
    for (int o = 1; o < 1024; o <<= 1) {
        int t = (tid >= o) ? sm[tid - o] : 0;
        __syncthreads();
        sm[tid] += t;
        __syncthreads();
    }
    if (tid < nb) bpref[tid] = sm[tid] - v;
}

// writes scan result for g<n; pads offs[n .. n+1024] = total (for per-block LDS staging)
__global__ __launch_bounds__(512) void scan3(int* __restrict__ offs, int* __restrict__ cursor,
                                             const int* __restrict__ bpref, int n, int total) {
    int g = blockIdx.x * 512 + threadIdx.x;
    if (g < n) {
        int v = offs[g] + bpref[blockIdx.x];
        offs[g] = v;
        cursor[g] = v;
    } else if (g <= n + 1024) {
        offs[g] = total;
    }
}

__global__ void scatter_edges(const int* __restrict__ dst, const int* __restrict__ rel,
                              const int* __restrict__ src, int* __restrict__ cursor,
                              int* __restrict__ csr, int E) {
    int e = blockIdx.x * 256 + threadIdx.x;
    if (e >= E) return;
    int seg = dst[e] * NR + rel[e];
    int pos = atomicAdd(&cursor[seg], 1);
    csr[pos] = src[e];
}

// ---------------- triple sort by s-bucket (decoder L2 locality) ----------------

__global__ void hist_triples(const int* __restrict__ src, const int* __restrict__ nsrc,
                             int* __restrict__ hist) {
    int t = blockIdx.x * 256 + threadIdx.x;
    if (t >= 2 * NE) return;
    int s = (t < NE) ? src[t] : nsrc[t - NE];
    atomicAdd(&hist[s >> 6], 1);
}

__global__ __launch_bounds__(1024) void scan_hist(const int* __restrict__ hist,
                                                  int* __restrict__ cur) {
    __shared__ int sm[1024];
    int tid = threadIdx.x;
    int v = (tid < NBK) ? hist[tid] : 0;
    sm[tid] = v;
    __syncthreads();
    for (int o = 1; o < 1024; o <<= 1) {
        int t = (tid >= o) ? sm[tid - o] : 0;
        __syncthreads();
        sm[tid] += t;
        __syncthreads();
    }
    if (tid < NBK) cur[tid] = sm[tid] - v;
}

__global__ void scatter_triples(const int* __restrict__ src, const int* __restrict__ dst,
                                const int* __restrict__ rel, const int* __restrict__ nsrc,
                                const int* __restrict__ ndst, const int* __restrict__ nrel,
                                int* __restrict__ cur, int* __restrict__ ss, int* __restrict__ so,
                                int* __restrict__ sr, int* __restrict__ st) {
    int t = blockIdx.x * 256 + threadIdx.x;
    if (t >= 2 * NE) return;
    int s, o, r;
    if (t < NE) { s = src[t]; o = dst[t]; r = rel[t]; }
    else { int u = t - NE; s = nsrc[u]; o = ndst[u]; r = nrel[u]; }
    int pos = atomicAdd(&cur[s >> 6], 1);
    ss[pos] = s; so[pos] = o; sr[pos] = r; st[pos] = t;
}

// ---------------- converts ----------------

__global__ void f32_to_f16_vec(const float* __restrict__ in, _Float16* __restrict__ out, long n4) {
    long i = (long)blockIdx.x * 256 + threadIdx.x;
    long stride = (long)gridDim.x * 256;
    for (; i < n4; i += stride) {
        float4 v = ((const float4*)in)[i];
        half4 h;
        h[0] = (_Float16)v.x; h[1] = (_Float16)v.y; h[2] = (_Float16)v.z; h[3] = (_Float16)v.w;
        ((half4*)out)[i] = h;
    }
}

// Bt[n][k] = (k<K0 ? S0[k][n] : S1[k-K0][n]), fp32 -> fp16. 32x32 LDS tile transpose.
__global__ __launch_bounds__(256) void build_bt(const float* __restrict__ S0, int K0,
                                                const float* __restrict__ S1,
                                                _Float16* __restrict__ Bt, int N, int K) {
    __shared__ float tile[32][33];
    const int kb = blockIdx.x * 32, nb = blockIdx.y * 32;
    const int tx = threadIdx.x & 31, ty = threadIdx.x >> 5;
#pragma unroll
    for (int i = 0; i < 32; i += 8) {
        int k = kb + ty + i, n = nb + tx;
        float v = 0.f;
        if (k < K && n < N) v = (k < K0) ? S0[(size_t)k * N + n] : S1[(size_t)(k - K0) * N + n];
        tile[ty + i][tx] = v;
    }
    __syncthreads();
#pragma unroll
    for (int i = 0; i < 32; i += 8) {
        int n = nb + ty + i, k = kb + tx;
        if (n < N && k < K) Bt[(size_t)n * K + k] = (_Float16)tile[tx][ty + i];
    }
}

// ---------------- fused RGCN layer (round-13: wave-private Bs, packed-fp16 build) ----------------

template <bool RELU, bool LAST>
__global__ __launch_bounds__(512, 4) void rgcn_layer(
    const _Float16* __restrict__ x, const _Float16* __restrict__ Bt,
    const int* __restrict__ csr, const int* __restrict__ offs,
    const float* __restrict__ bias,
    _Float16* __restrict__ C16, int ldc, float* __restrict__ C32, int N) {
    __shared__ _Float16 As[64 * 256];     // 32 KB
    __shared__ _Float16 Bs[2][256 * 32];  // 2 x 16 KB; wave w owns rows [32w,32w+32)
    __shared__ int offs_lds[520];
    __shared__ int csr_lds[CSR_CAP];
    const int tid = threadIdx.x;
    const int lane = tid & 63, wave = tid >> 6;
    const int lane32 = tid & 31, hw = tid >> 5;
    const int half_base = lane & 32;
    const int l15 = lane & 15, q = lane >> 4;
    const int m0 = blockIdx.x * 64;
    const int segbase = m0 * NR;

    for (int i = tid; i < 513; i += 512) offs_lds[i] = offs[segbase + i];
    __syncthreads();
    const int e0 = offs_lds[0];
    const int e1 = offs_lds[512];
    const int ecnt = min(e1 - e0, CSR_CAP);
    for (int i = tid; i < ecnt; i += 512) csr_lds[i] = csr[e0 + i];
    __syncthreads();

    auto stage = [&](int buf, int g) {
        int kbase = g * 32;
#pragma unroll
        for (int h = 0; h < 2; ++h) {
            int s = lane + h * 64;
            int n = wave * 32 + (s >> 2);
            int c4 = s & 3;
            int nn = n < N ? n : N - 1;
            gload16(Bt + (size_t)nn * 2304 + kbase + ((c4 ^ (n & 3)) << 3),
                    &Bs[buf][wave * 1024 + h * 512]);
        }
    };

    f32x4 acc[4][2] = {};
    stage(0, 0);
    int cur = 0;
    for (int seg = 0; seg < 9; ++seg) {
#pragma unroll
        for (int u = 0; u < 4; ++u) {
            int lr = u * 16 + hw;
            int nd = m0 + lr;
            if (nd >= NN) nd = NN - 1;
            half8 hv;
            if (seg == 0) {
                hv = *(const half8*)(x + (size_t)nd * 256 + lane32 * 8);
            } else {
                int sb = lr * NR + seg - 1;
                int o0 = offs_lds[sb], o1 = offs_lds[sb + 1];
                int n = o1 - o0;
                if (n < 0) n = 0;
                if (n == 0) {
#pragma unroll
                    for (int z = 0; z < 8; ++z) hv[z] = (_Float16)0.f;
                } else {
                    bool staged = (o1 - e0) <= CSR_CAP;
                    int fi = o0 + (lane32 < n ? lane32 : n - 1);
                    int idxv = staged ? csr_lds[fi - e0] : csr[fi];
                    half8 sA = {}, sB = {};
                    int nb = n < 32 ? n : 32;
                    int e = 0;
                    for (; e + 4 <= nb; e += 4) {
                        int s0 = __shfl(idxv, half_base + e);
                        int s1 = __shfl(idxv, half_base + e + 1);
                        int s2 = __shfl(idxv, half_base + e + 2);
                        int s3 = __shfl(idxv, half_base + e + 3);
                        half8 v0 = *(const half8*)(x + (size_t)s0 * 256 + lane32 * 8);
                        half8 v1 = *(const half8*)(x + (size_t)s1 * 256 + lane32 * 8);
                        half8 v2 = *(const half8*)(x + (size_t)s2 * 256 + lane32 * 8);
                        half8 v3 = *(const half8*)(x + (size_t)s3 * 256 + lane32 * 8);
                        sA += v0 + v1;
                        sB += v2 + v3;
                    }
                    for (; e < nb; ++e) {
                        int s0 = __shfl(idxv, half_base + e);
                        half8 v0 = *(const half8*)(x + (size_t)s0 * 256 + lane32 * 8);
                        sA += v0;
                    }
                    for (int e2 = 32; e2 < n; ++e2) {
                        int s2i = staged ? csr_lds[o0 - e0 + e2] : csr[o0 + e2];
                        half8 v = *(const half8*)(x + (size_t)s2i * 256 + lane32 * 8);
                        sB += v;
                    }
                    _Float16 hinv = (_Float16)(1.0f / (float)n);
                    hv = (sA + sB) * hinv;
                }
            }
            *(half8*)((char*)As + lr * 512 + ((lane32 ^ (lr & 31)) << 4)) = hv;
        }
        asm volatile("s_waitcnt lgkmcnt(0)" ::: "memory");
        __builtin_amdgcn_s_barrier();
        asm volatile("" ::: "memory");
#pragma unroll
        for (int ch = 0; ch < 8; ++ch) {
            int g = seg * 8 + ch;
            if (g < 71) {
                stage(cur ^ 1, g + 1);
                asm volatile("s_waitcnt vmcnt(2)" ::: "memory");
            } else {
                asm volatile("s_waitcnt vmcnt(0)" ::: "memory");
            }
            half8 a[4], b[2];
#pragma unroll
            for (int i = 0; i < 4; ++i) {
                int row = i * 16 + l15;
                int ck = ch * 4 + q;
                a[i] = *(const half8*)((const char*)As + row * 512 + ((ck ^ (row & 31)) << 4));
            }
#pragma unroll
            for (int j = 0; j < 2; ++j) {
                int n = wave * 32 + j * 16 + l15;
                b[j] = *(const half8*)((const char*)&Bs[cur][0] + n * 64 + ((q ^ (n & 3)) << 4));
            }
            __builtin_amdgcn_s_setprio(1);
#pragma unroll
            for (int i = 0; i < 4; ++i)
#pragma unroll
                for (int j = 0; j < 2; ++j)
                    acc[i][j] = __builtin_amdgcn_mfma_f32_16x16x32_f16(a[i], b[j], acc[i][j], 0, 0, 0);
            __builtin_amdgcn_s_setprio(0);
            cur ^= 1;
        }
        asm volatile("s_waitcnt lgkmcnt(0)" ::: "memory");
        __builtin_amdgcn_s_barrier();
        asm volatile("" ::: "memory");
    }
#pragma unroll
    for (int j = 0; j < 2; ++j) {
        int cc = wave * 32 + j * 16 + l15;
        if (cc >= N) continue;
        float bv = bias[cc];
#pragma unroll
        for (int i = 0; i < 4; ++i) {
            int rbase = m0 + i * 16 + q * 4;
#pragma unroll
            for (int t = 0; t < 4; ++t) {
                int rr = rbase + t;
                if (rr >= NN) continue;
                float v = acc[i][j][t] + bv;
                if (RELU) v = fmaxf(v, 0.f);
                C16[(size_t)rr * ldc + cc] = (_Float16)v;
                if (LAST) C32[(size_t)rr * ldc + cc] = v;
            }
        }
    }
}

// ---------------- fp16 MFMA GEMM (proj only), double-buffered LDS ----------------

template <bool BIAS, bool ACC_IN, bool FINAL, bool RELU, bool LAST, bool SCATTER>
__global__ __launch_bounds__(256) void gemm16(
    const _Float16* __restrict__ A, int lda,
    const _Float16* __restrict__ Bt, int ldb,
    const float* __restrict__ bias, const int* __restrict__ sidx,
    _Float16* __restrict__ Cacc,
    _Float16* __restrict__ C16, int ldc, float* __restrict__ C32,
    int M, int N, int K) {
    __shared__ _Float16 As[2][4096];
    __shared__ _Float16 Bs[2][4096];
    const int tid = threadIdx.x;
    const int lane = tid & 63, wave = tid >> 6;
    const int wm = wave >> 1, wn = wave & 1;
    const int q = lane >> 4, l15 = lane & 15;
    const int m0 = blockIdx.y * 128, n0 = blockIdx.x * 128;
    const int wbase = wave * 512;
    f32x4 acc[4][4] = {};

    auto stage = [&](int buf, int k0) {
#pragma unroll
        for (int h = 0; h < 2; ++h) {
            int s = tid + h * 256;
            int r = s >> 2, c = s & 3;
            int cs = c ^ ((r >> 2) & 3);
            int ga = m0 + r; if (ga >= M) ga = M - 1;
            gload16(A + (size_t)ga * lda + k0 + cs * 8, &As[buf][wbase + h * 2048]);
            int gb = n0 + r; if (gb >= N) gb = N - 1;
            gload16(Bt + (size_t)gb * ldb + k0 + cs * 8, &Bs[buf][wbase + h * 2048]);
        }
    };

    const int nk = K >> 5;
    stage(0, 0);
    int cur = 0;
    for (int kt = 0; kt < nk; ++kt) {
        if (kt + 1 < nk) {
            stage(cur ^ 1, (kt + 1) << 5);
            asm volatile("s_waitcnt vmcnt(4)" ::: "memory");
        } else {
            asm volatile("s_waitcnt vmcnt(0)" ::: "memory");
        }
        __builtin_amdgcn_s_barrier();
        asm volatile("" ::: "memory");
        half8 a[4], b[4];
#pragma unroll
        for (int i = 0; i < 4; ++i) {
            int row = wm * 64 + i * 16 + l15;
            a[i] = *(const half8*)&As[cur][row * 32 + ((q ^ ((row >> 2) & 3)) << 3)];
            int col = wn * 64 + i * 16 + l15;
            b[i] = *(const half8*)&Bs[cur][col * 32 + ((q ^ ((col >> 2) & 3)) << 3)];
        }
#pragma unroll
        for (int i = 0; i < 4; ++i)
#pragma unroll
            for (int j = 0; j < 4; ++j)
                acc[i][j] = __builtin_amdgcn_mfma_f32_16x16x32_f16(a[i], b[j], acc[i][j], 0, 0, 0);
        asm volatile("s_waitcnt lgkmcnt(0)" ::: "memory");
        __builtin_amdgcn_s_barrier();
        asm volatile("" ::: "memory");
        cur ^= 1;
    }
#pragma unroll
    for (int i = 0; i < 4; ++i) {
        int rbase = m0 + wm * 64 + i * 16 + q * 4;
#pragma unroll
        for (int j = 0; j < 4; ++j) {
            int cc = n0 + wn * 64 + j * 16 + l15;
            if (cc >= N) continue;
#pragma unroll
            for (int t = 0; t < 4; ++t) {
                int rr = rbase + t;
                if (rr >= M) continue;
                float v = acc[i][j][t];
                if (BIAS) v += bias[cc];
                if (ACC_IN) v += (float)Cacc[(size_t)rr * 256 + cc];
                if (!FINAL) {
                    Cacc[(size_t)rr * 256 + cc] = (_Float16)v;
                } else {
                    if (RELU) v = fmaxf(v, 0.f);
                    int ro = SCATTER ? sidx[rr] : rr;
                    C16[(size_t)ro * ldc + cc] = (_Float16)v;
                    if (LAST) C32[(size_t)ro * ldc + cc] = v;
                }
            }
        }
    }
}

// ---------------- DistMult decoder (sorted triples, fp16 packed math, 8 lanes/triple) ----------------

__global__ __launch_bounds__(256) void decoder16s(
    const _Float16* __restrict__ out16, const _Float16* __restrict__ rel16,
    const int* __restrict__ ss, const int* __restrict__ so, const int* __restrict__ sr,
    const int* __restrict__ st, float* __restrict__ scores) {
    __shared__ _Float16 rel_lds[NR * OUTD];  // 3.2 KB
    if (threadIdx.x < 200) {
        int rr = threadIdx.x / 25, cc = threadIdx.x % 25;
        *(half8*)&rel_lds[rr * OUTD + cc * 8] = *(const half8*)(rel16 + (size_t)rr * OUTD + cc * 8);
    }
    __syncthreads();
    int gid = blockIdx.x * 256 + threadIdx.x;
    int t = gid >> 3, lq = gid & 7;
    if (t >= 2 * NE) return;
    int s = ss[t], o = so[t], r = sr[t];
    const half8* ps = (const half8*)(out16 + (size_t)s * OUTD);
    const half8* po = (const half8*)(out16 + (size_t)o * OUTD);
    const _Float16* pr = rel_lds + r * OUTD;
    half8 hacc0 = {}, hacc1 = {};
#pragma unroll
    for (int it = 0; it < 4; ++it) {
        int c = it * 8 + lq;
        if (c < 25) {
            half8 a = ps[c], d = po[c];
            half8 b = *(const half8*)(pr + c * 8);
            half8 p = a * b * d;
            if (it & 1) hacc1 += p; else hacc0 += p;
        }
    }
    float acc = 0.f;
#pragma unroll
    for (int u = 0; u < 8; ++u) acc += (float)hacc0[u] + (float)hacc1[u];
#pragma unroll
    for (int off = 4; off; off >>= 1) acc += __shfl_xor(acc, off);
    if (lq == 0) scores[st[t]] = acc;  // random 4B writes into 6.4MB L2-resident region
}

// ---------------- host ----------------

extern "C" void kernel_launch(void* const* d_in, const int* in_sizes, int n_in,
                              void* d_out, int out_size, void* d_ws, size_t ws_size,
                              hipStream_t stream) {
    const float* emb   = (const float*)d_in[0];
    const int*   nidx  = (const int*)d_in[1];
    const int*   src   = (const int*)d_in[2];
    const int*   dst   = (const int*)d_in[3];
    const int*   rel   = (const int*)d_in[4];
    const int*   nsrc  = (const int*)d_in[5];
    const int*   ndst  = (const int*)d_in[6];
    const int*   nrel  = (const int*)d_in[7];
    const float* Wp    = (const float*)d_in[8];
    const float* bp    = (const float*)d_in[9];
    const float* W0    = (const float*)d_in[10];
    const float* root0 = (const float*)d_in[11];
    const float* b0    = (const float*)d_in[12];
    const float* W1    = (const float*)d_in[13];
    const float* root1 = (const float*)d_in[14];
    const float* b1    = (const float*)d_in[15];
    const float* W2    = (const float*)d_in[16];
    const float* root2 = (const float*)d_in[17];
    const float* b2    = (const float*)d_in[18];
    const float* rele  = (const float*)d_in[19];
    (void)in_sizes; (void)n_in; (void)out_size; (void)ws_size;

    float* out    = (float*)d_out;            // [NN][OUTD]
    float* scores = out + (size_t)NN * OUTD;  // [2*NE]

    auto align = [](size_t x) { return (x + 255) & ~(size_t)255; };
    char* p = (char*)d_ws;
    auto alloc = [&](size_t bytes) -> char* {
        char* q = p; p += align(bytes); return q;
    };
    _Float16* emb16  = (_Float16*)alloc((size_t)NN * EMBD * 2);
    _Float16* xbufA  = (_Float16*)alloc((size_t)NN * 256 * 2);
    _Float16* xbufB  = (_Float16*)alloc((size_t)NN * 256 * 2);
    _Float16* out16  = xbufB;  // L2 output aliases xbufB (dead by then)
    _Float16* Bt0 = (_Float16*)alloc((size_t)256 * 2304 * 2);
    _Float16* Bt1 = (_Float16*)alloc((size_t)256 * 2304 * 2);
    _Float16* Bt2 = (_Float16*)alloc((size_t)256 * 2304 * 2);
    _Float16* BtP = (_Float16*)alloc((size_t)256 * EMBD * 2);
    _Float16* rel16 = (_Float16*)alloc((size_t)NR * OUTD * 2);
    int*   cnt    = (int*)alloc((size_t)NSEG * 4);
    int*   cursor = (int*)alloc((size_t)NSEG * 4);
    int*   offs   = (int*)alloc((size_t)(NSEG + 1032) * 4);  // padded for block staging
    int*   csr    = (int*)alloc((size_t)NE * 4);
    int*   bsums  = (int*)alloc(4096);
    int*   bpref  = (int*)alloc(4096);
    int*   ss     = (int*)alloc((size_t)2 * NE * 4);  // sorted triples
    int*   so     = (int*)alloc((size_t)2 * NE * 4);
    int*   sr     = (int*)alloc((size_t)2 * NE * 4);
    int*   st     = (int*)alloc((size_t)2 * NE * 4);
    int*   bhist  = (int*)alloc(NBK * 4);
    int*   bcur   = (int*)alloc(NBK * 4);

    // --- CSR build ---
    hipMemsetAsync(cnt, 0, (size_t)NSEG * 4, stream);
    count_edges<<<(NE + 255) / 256, 256, 0, stream>>>(dst, rel, cnt, NE);
    const int NB = (NSEG + 511) / 512;
    scan1<<<NB, 512, 0, stream>>>(cnt, offs, bsums, NSEG);
    scan2<<<1, 1024, 0, stream>>>(bsums, bpref, NB);
    scan3<<<NB + 3, 512, 0, stream>>>(offs, cursor, bpref, NSEG, NE);  // includes pad
    scatter_edges<<<(NE + 255) / 256, 256, 0, stream>>>(dst, rel, src, cursor, csr, NE);

    // --- triple sort by s-bucket (decoder locality) ---
    hipMemsetAsync(bhist, 0, NBK * 4, stream);
    hist_triples<<<(2 * NE + 255) / 256, 256, 0, stream>>>(src, nsrc, bhist);
    scan_hist<<<1, 1024, 0, stream>>>(bhist, bcur);
    scatter_triples<<<(2 * NE + 255) / 256, 256, 0, stream>>>(src, dst, rel, nsrc, ndst, nrel,
                                                              bcur, ss, so, sr, st);

    // --- weight/embedding converts (tiled transpose, coalesced both sides) ---
    f32_to_f16_vec<<<2048, 256, 0, stream>>>(emb, emb16, (long)NN * EMBD / 4);
    f32_to_f16_vec<<<2, 256, 0, stream>>>(rele, rel16, (long)NR * OUTD / 4);
    build_bt<<<dim3(16, 8), 256, 0, stream>>>(Wp, EMBD, nullptr, BtP, PROJD, EMBD);
    build_bt<<<dim3(72, 8), 256, 0, stream>>>(root0, 256, W0, Bt0, HIDD, 2304);
    build_bt<<<dim3(72, 8), 256, 0, stream>>>(root1, 256, W1, Bt1, HIDD, 2304);
    build_bt<<<dim3(72, 7), 256, 0, stream>>>(root2, 256, W2, Bt2, OUTD, 2304);

    // --- projection: xbufA[nidx[i]] = fp16(emb[i] @ Wp + bp) ---
    {
        dim3 g(2, (NN + 127) / 128);
        gemm16<true, false, true, false, false, true><<<g, 256, 0, stream>>>(
            emb16, EMBD, BtP, EMBD, bp, nidx, nullptr, xbufA, 256, nullptr, NN, 256, EMBD);
    }

    // --- fused RGCN layers ---
    const int GL = (NN + 63) / 64;
    rgcn_layer<true, false><<<GL, 512, 0, stream>>>(xbufA, Bt0, csr, offs, b0,
                                                    xbufB, 256, nullptr, HIDD);
    rgcn_layer<true, false><<<GL, 512, 0, stream>>>(xbufB, Bt1, csr, offs, b1,
                                                    xbufA, 256, nullptr, HIDD);
    rgcn_layer<false, true><<<GL, 512, 0, stream>>>(xbufA, Bt2, csr, offs, b2,
                                                    out16, OUTD, out, OUTD);

    // --- decoder (sorted order) ---
    decoder16s<<<(2 * NE * 8 + 255) / 256, 256, 0, stream>>>(out16, rel16, ss, so, sr, st,
                                                             scores);
}

// Round 16
// 825.808 us; speedup vs baseline: 1.8678x; 1.8678x over previous
//
#include <hip/hip_runtime.h>
#include <stdint.h>

#define NN 50000
#define NE 800000
#define NR 8
#define EMBD 512
#define PROJD 256
#define HIDD 256
#define OUTD 200
#define NSEG (NN * NR)
#define CSR_CAP 1536

typedef _Float16 half8 __attribute__((ext_vector_type(8)));
typedef _Float16 half4 __attribute__((ext_vector_type(4)));
typedef float f32x4 __attribute__((ext_vector_type(4)));

// ---------------- async global->LDS ----------------
__device__ __forceinline__ void gload16(const void* g, void* l) {
    __builtin_amdgcn_global_load_lds(
        reinterpret_cast<const __attribute__((address_space(1))) uint32_t*>(
            reinterpret_cast<uintptr_t>(g)),
        reinterpret_cast<__attribute__((address_space(3))) uint32_t*>(
            reinterpret_cast<uintptr_t>(l)),
        16, 0, 0);
}

// ---------------- CSR build ----------------

__global__ void count_edges(const int* __restrict__ dst, const int* __restrict__ rel,
                            int* __restrict__ cnt, int E) {
    int e = blockIdx.x * 256 + threadIdx.x;
    if (e >= E) return;
    atomicAdd(&cnt[dst[e] * NR + rel[e]], 1);
}

__global__ __launch_bounds__(512) void scan1(const int* __restrict__ cnt, int* __restrict__ offs,
                                             int* __restrict__ bsums, int n) {
    __shared__ int sm[512];
    int tid = threadIdx.x;
    int g = blockIdx.x * 512 + tid;
    int v = (g < n) ? cnt[g] : 0;
    sm[tid] = v;
    __syncthreads();
    for (int o = 1; o < 512; o <<= 1) {
        int t = (tid >= o) ? sm[tid - o] : 0;
        __syncthreads();
        sm[tid] += t;
        __syncthreads();
    }
    if (g < n) offs[g] = sm[tid] - v;
    if (tid == 511) bsums[blockIdx.x] = sm[511];
}

__global__ __launch_bounds__(1024) void scan2(const int* __restrict__ bsums, int* __restrict__ bpref, int nb) {
    __shared__ int sm[1024];
    int tid = threadIdx.x;
    int v = (tid < nb) ? bsums[tid] : 0;
    sm[tid] = v;
    __syncthreads();
    for (int o = 1; o < 1024; o <<= 1) {
        int t = (tid >= o) ? sm[tid - o] : 0;
        __syncthreads();
        sm[tid] += t;
        __syncthreads();
    }
    if (tid < nb) bpref[tid] = sm[tid] - v;
}

// writes scan result for g<n; pads offs[n .. n+1024] = total (for per-block LDS staging)
__global__ __launch_bounds__(512) void scan3(int* __restrict__ offs, int* __restrict__ cursor,
                                             const int* __restrict__ bpref, int n, int total) {
    int g = blockIdx.x * 512 + threadIdx.x;
    if (g < n) {
        int v = offs[g] + bpref[blockIdx.x];
        offs[g] = v;
        cursor[g] = v;
    } else if (g <= n + 1024) {
        offs[g] = total;
    }
}

__global__ void scatter_edges(const int* __restrict__ dst, const int* __restrict__ rel,
                              const int* __restrict__ src, int* __restrict__ cursor,
                              int* __restrict__ csr, int E) {
    int e = blockIdx.x * 256 + threadIdx.x;
    if (e >= E) return;
    int seg = dst[e] * NR + rel[e];
    int pos = atomicAdd(&cursor[seg], 1);
    csr[pos] = src[e];
}

// ---------------- converts ----------------

__global__ void f32_to_f16_vec(const float* __restrict__ in, _Float16* __restrict__ out, long n4) {
    long i = (long)blockIdx.x * 256 + threadIdx.x;
    long stride = (long)gridDim.x * 256;
    for (; i < n4; i += stride) {
        float4 v = ((const float4*)in)[i];
        half4 h;
        h[0] = (_Float16)v.x; h[1] = (_Float16)v.y; h[2] = (_Float16)v.z; h[3] = (_Float16)v.w;
        ((half4*)out)[i] = h;
    }
}

// Bt[n][k] = (k<K0 ? S0[k][n] : S1[k-K0][n]), fp32 -> fp16. 32x32 LDS tile transpose.
__global__ __launch_bounds__(256) void build_bt(const float* __restrict__ S0, int K0,
                                                const float* __restrict__ S1,
                                                _Float16* __restrict__ Bt, int N, int K) {
    __shared__ float tile[32][33];
    const int kb = blockIdx.x * 32, nb = blockIdx.y * 32;
    const int tx = threadIdx.x & 31, ty = threadIdx.x >> 5;
#pragma unroll
    for (int i = 0; i < 32; i += 8) {
        int k = kb + ty + i, n = nb + tx;
        float v = 0.f;
        if (k < K && n < N) v = (k < K0) ? S0[(size_t)k * N + n] : S1[(size_t)(k - K0) * N + n];
        tile[ty + i][tx] = v;
    }
    __syncthreads();
#pragma unroll
    for (int i = 0; i < 32; i += 8) {
        int n = nb + ty + i, k = kb + tx;
        if (n < N && k < K) Bt[(size_t)n * K + k] = (_Float16)tile[tx][ty + i];
    }
}

// ---------------- fused RGCN layer (round-13: wave-private Bs, packed-fp16 build) ----------------

template <bool RELU, bool LAST>
__global__ __launch_bounds__(512, 4) void rgcn_layer(
    const _Float16* __restrict__ x, const _Float16* __restrict__ Bt,
    const int* __restrict__ csr, const int* __restrict__ offs,
    const float* __restrict__ bias,
    _Float16* __restrict__ C16, int ldc, float* __restrict__ C32, int N) {
    __shared__ _Float16 As[64 * 256];     // 32 KB
    __shared__ _Float16 Bs[2][256 * 32];  // 2 x 16 KB; wave w owns rows [32w,32w+32)
    __shared__ int offs_lds[520];
    __shared__ int csr_lds[CSR_CAP];
    const int tid = threadIdx.x;
    const int lane = tid & 63, wave = tid >> 6;
    const int lane32 = tid & 31, hw = tid >> 5;
    const int half_base = lane & 32;
    const int l15 = lane & 15, q = lane >> 4;
    const int m0 = blockIdx.x * 64;
    const int segbase = m0 * NR;

    for (int i = tid; i < 513; i += 512) offs_lds[i] = offs[segbase + i];
    __syncthreads();
    const int e0 = offs_lds[0];
    const int e1 = offs_lds[512];
    const int ecnt = min(e1 - e0, CSR_CAP);
    for (int i = tid; i < ecnt; i += 512) csr_lds[i] = csr[e0 + i];
    __syncthreads();

    auto stage = [&](int buf, int g) {
        int kbase = g * 32;
#pragma unroll
        for (int h = 0; h < 2; ++h) {
            int s = lane + h * 64;
            int n = wave * 32 + (s >> 2);
            int c4 = s & 3;
            int nn = n < N ? n : N - 1;
            gload16(Bt + (size_t)nn * 2304 + kbase + ((c4 ^ (n & 3)) << 3),
                    &Bs[buf][wave * 1024 + h * 512]);
        }
    };

    f32x4 acc[4][2] = {};
    stage(0, 0);
    int cur = 0;
    for (int seg = 0; seg < 9; ++seg) {
#pragma unroll
        for (int u = 0; u < 4; ++u) {
            int lr = u * 16 + hw;
            int nd = m0 + lr;
            if (nd >= NN) nd = NN - 1;
            half8 hv;
            if (seg == 0) {
                hv = *(const half8*)(x + (size_t)nd * 256 + lane32 * 8);
            } else {
                int sb = lr * NR + seg - 1;
                int o0 = offs_lds[sb], o1 = offs_lds[sb + 1];
                int n = o1 - o0;
                if (n < 0) n = 0;
                if (n == 0) {
#pragma unroll
                    for (int z = 0; z < 8; ++z) hv[z] = (_Float16)0.f;
                } else {
                    bool staged = (o1 - e0) <= CSR_CAP;
                    int fi = o0 + (lane32 < n ? lane32 : n - 1);
                    int idxv = staged ? csr_lds[fi - e0] : csr[fi];
                    half8 sA = {}, sB = {};
                    int nb = n < 32 ? n : 32;
                    int e = 0;
                    for (; e + 4 <= nb; e += 4) {
                        int s0 = __shfl(idxv, half_base + e);
                        int s1 = __shfl(idxv, half_base + e + 1);
                        int s2 = __shfl(idxv, half_base + e + 2);
                        int s3 = __shfl(idxv, half_base + e + 3);
                        half8 v0 = *(const half8*)(x + (size_t)s0 * 256 + lane32 * 8);
                        half8 v1 = *(const half8*)(x + (size_t)s1 * 256 + lane32 * 8);
                        half8 v2 = *(const half8*)(x + (size_t)s2 * 256 + lane32 * 8);
                        half8 v3 = *(const half8*)(x + (size_t)s3 * 256 + lane32 * 8);
                        sA += v0 + v1;
                        sB += v2 + v3;
                    }
                    for (; e < nb; ++e) {
                        int s0 = __shfl(idxv, half_base + e);
                        half8 v0 = *(const half8*)(x + (size_t)s0 * 256 + lane32 * 8);
                        sA += v0;
                    }
                    for (int e2 = 32; e2 < n; ++e2) {
                        int s2i = staged ? csr_lds[o0 - e0 + e2] : csr[o0 + e2];
                        half8 v = *(const half8*)(x + (size_t)s2i * 256 + lane32 * 8);
                        sB += v;
                    }
                    _Float16 hinv = (_Float16)(1.0f / (float)n);
                    hv = (sA + sB) * hinv;
                }
            }
            *(half8*)((char*)As + lr * 512 + ((lane32 ^ (lr & 31)) << 4)) = hv;
        }
        asm volatile("s_waitcnt lgkmcnt(0)" ::: "memory");
        __builtin_amdgcn_s_barrier();
        asm volatile("" ::: "memory");
#pragma unroll
        for (int ch = 0; ch < 8; ++ch) {
            int g = seg * 8 + ch;
            if (g < 71) {
                stage(cur ^ 1, g + 1);
                asm volatile("s_waitcnt vmcnt(2)" ::: "memory");
            } else {
                asm volatile("s_waitcnt vmcnt(0)" ::: "memory");
            }
            half8 a[4], b[2];
#pragma unroll
            for (int i = 0; i < 4; ++i) {
                int row = i * 16 + l15;
                int ck = ch * 4 + q;
                a[i] = *(const half8*)((const char*)As + row * 512 + ((ck ^ (row & 31)) << 4));
            }
#pragma unroll
            for (int j = 0; j < 2; ++j) {
                int n = wave * 32 + j * 16 + l15;
                b[j] = *(const half8*)((const char*)&Bs[cur][0] + n * 64 + ((q ^ (n & 3)) << 4));
            }
            __builtin_amdgcn_s_setprio(1);
#pragma unroll
            for (int i = 0; i < 4; ++i)
#pragma unroll
                for (int j = 0; j < 2; ++j)
                    acc[i][j] = __builtin_amdgcn_mfma_f32_16x16x32_f16(a[i], b[j], acc[i][j], 0, 0, 0);
            __builtin_amdgcn_s_setprio(0);
            cur ^= 1;
        }
        asm volatile("s_waitcnt lgkmcnt(0)" ::: "memory");
        __builtin_amdgcn_s_barrier();
        asm volatile("" ::: "memory");
    }
#pragma unroll
    for (int j = 0; j < 2; ++j) {
        int cc = wave * 32 + j * 16 + l15;
        if (cc >= N) continue;
        float bv = bias[cc];
#pragma unroll
        for (int i = 0; i < 4; ++i) {
            int rbase = m0 + i * 16 + q * 4;
#pragma unroll
            for (int t = 0; t < 4; ++t) {
                int rr = rbase + t;
                if (rr >= NN) continue;
                float v = acc[i][j][t] + bv;
                if (RELU) v = fmaxf(v, 0.f);
                C16[(size_t)rr * ldc + cc] = (_Float16)v;
                if (LAST) C32[(size_t)rr * ldc + cc] = v;
            }
        }
    }
}

// ---------------- fp16 MFMA GEMM (proj only), double-buffered LDS ----------------

template <bool BIAS, bool ACC_IN, bool FINAL, bool RELU, bool LAST, bool SCATTER>
__global__ __launch_bounds__(256) void gemm16(
    const _Float16* __restrict__ A, int lda,
    const _Float16* __restrict__ Bt, int ldb,
    const float* __restrict__ bias, const int* __restrict__ sidx,
    _Float16* __restrict__ Cacc,
    _Float16* __restrict__ C16, int ldc, float* __restrict__ C32,
    int M, int N, int K) {
    __shared__ _Float16 As[2][4096];
    __shared__ _Float16 Bs[2][4096];
    const int tid = threadIdx.x;
    const int lane = tid & 63, wave = tid >> 6;
    const int wm = wave >> 1, wn = wave & 1;
    const int q = lane >> 4, l15 = lane & 15;
    const int m0 = blockIdx.y * 128, n0 = blockIdx.x * 128;
    const int wbase = wave * 512;
    f32x4 acc[4][4] = {};

    auto stage = [&](int buf, int k0) {
#pragma unroll
        for (int h = 0; h < 2; ++h) {
            int s = tid + h * 256;
            int r = s >> 2, c = s & 3;
            int cs = c ^ ((r >> 2) & 3);
            int ga = m0 + r; if (ga >= M) ga = M - 1;
            gload16(A + (size_t)ga * lda + k0 + cs * 8, &As[buf][wbase + h * 2048]);
            int gb = n0 + r; if (gb >= N) gb = N - 1;
            gload16(Bt + (size_t)gb * ldb + k0 + cs * 8, &Bs[buf][wbase + h * 2048]);
        }
    };

    const int nk = K >> 5;
    stage(0, 0);
    int cur = 0;
    for (int kt = 0; kt < nk; ++kt) {
        if (kt + 1 < nk) {
            stage(cur ^ 1, (kt + 1) << 5);
            asm volatile("s_waitcnt vmcnt(4)" ::: "memory");
        } else {
            asm volatile("s_waitcnt vmcnt(0)" ::: "memory");
        }
        __builtin_amdgcn_s_barrier();
        asm volatile("" ::: "memory");
        half8 a[4], b[4];
#pragma unroll
        for (int i = 0; i < 4; ++i) {
            int row = wm * 64 + i * 16 + l15;
            a[i] = *(const half8*)&As[cur][row * 32 + ((q ^ ((row >> 2) & 3)) << 3)];
            int col = wn * 64 + i * 16 + l15;
            b[i] = *(const half8*)&Bs[cur][col * 32 + ((q ^ ((col >> 2) & 3)) << 3)];
        }
#pragma unroll
        for (int i = 0; i < 4; ++i)
#pragma unroll
            for (int j = 0; j < 4; ++j)
                acc[i][j] = __builtin_amdgcn_mfma_f32_16x16x32_f16(a[i], b[j], acc[i][j], 0, 0, 0);
        asm volatile("s_waitcnt lgkmcnt(0)" ::: "memory");
        __builtin_amdgcn_s_barrier();
        asm volatile("" ::: "memory");
        cur ^= 1;
    }
#pragma unroll
    for (int i = 0; i < 4; ++i) {
        int rbase = m0 + wm * 64 + i * 16 + q * 4;
#pragma unroll
        for (int j = 0; j < 4; ++j) {
            int cc = n0 + wn * 64 + j * 16 + l15;
            if (cc >= N) continue;
#pragma unroll
            for (int t = 0; t < 4; ++t) {
                int rr = rbase + t;
                if (rr >= M) continue;
                float v = acc[i][j][t];
                if (BIAS) v += bias[cc];
                if (ACC_IN) v += (float)Cacc[(size_t)rr * 256 + cc];
                if (!FINAL) {
                    Cacc[(size_t)rr * 256 + cc] = (_Float16)v;
                } else {
                    if (RELU) v = fmaxf(v, 0.f);
                    int ro = SCATTER ? sidx[rr] : rr;
                    C16[(size_t)ro * ldc + cc] = (_Float16)v;
                    if (LAST) C32[(size_t)ro * ldc + cc] = v;
                }
            }
        }
    }
}

// ---------------- DistMult decoder (fp16 packed math, rel table in LDS) ----------------

__global__ __launch_bounds__(256) void decoder16(
    const _Float16* __restrict__ out16, const _Float16* __restrict__ rel16,
    const int* __restrict__ src, const int* __restrict__ dst, const int* __restrict__ rel,
    const int* __restrict__ nsrc, const int* __restrict__ ndst, const int* __restrict__ nrel,
    float* __restrict__ scores) {
    __shared__ _Float16 rel_lds[NR * OUTD];  // 3.2 KB
    if (threadIdx.x < 200) {
        int rr = threadIdx.x / 25, cc = threadIdx.x % 25;
        *(half8*)&rel_lds[rr * OUTD + cc * 8] = *(const half8*)(rel16 + (size_t)rr * OUTD + cc * 8);
    }
    __syncthreads();
    int gid = blockIdx.x * 256 + threadIdx.x;
    int t = gid >> 3, lq = gid & 7;
    if (t >= 2 * NE) return;
    int s, o, r;
    if (t < NE) { s = src[t]; o = dst[t]; r = rel[t]; }
    else { int u = t - NE; s = nsrc[u]; o = ndst[u]; r = nrel[u]; }
    const half8* ps = (const half8*)(out16 + (size_t)s * OUTD);
    const half8* po = (const half8*)(out16 + (size_t)o * OUTD);
    const _Float16* pr = rel_lds + r * OUTD;
    half8 hacc0 = {}, hacc1 = {};  // parity-split: <=2 products per fp16 slot
#pragma unroll
    for (int it = 0; it < 4; ++it) {
        int c = it * 8 + lq;
        if (c < 25) {
            half8 a = ps[c], d = po[c];
            half8 b = *(const half8*)(pr + c * 8);
            half8 p = a * b * d;
            if (it & 1) hacc1 += p; else hacc0 += p;
        }
    }
    float acc = 0.f;
#pragma unroll
    for (int u = 0; u < 8; ++u) acc += (float)hacc0[u] + (float)hacc1[u];
#pragma unroll
    for (int off = 4; off; off >>= 1) acc += __shfl_xor(acc, off);
    if (lq == 0) scores[t] = acc;
}

// ---------------- host ----------------

extern "C" void kernel_launch(void* const* d_in, const int* in_sizes, int n_in,
                              void* d_out, int out_size, void* d_ws, size_t ws_size,
                              hipStream_t stream) {
    const float* emb   = (const float*)d_in[0];
    const int*   nidx  = (const int*)d_in[1];
    const int*   src   = (const int*)d_in[2];
    const int*   dst   = (const int*)d_in[3];
    const int*   rel   = (const int*)d_in[4];
    const int*   nsrc  = (const int*)d_in[5];
    const int*   ndst  = (const int*)d_in[6];
    const int*   nrel  = (const int*)d_in[7];
    const float* Wp    = (const float*)d_in[8];
    const float* bp    = (const float*)d_in[9];
    const float* W0    = (const float*)d_in[10];
    const float* root0 = (const float*)d_in[11];
    const float* b0    = (const float*)d_in[12];
    const float* W1    = (const float*)d_in[13];
    const float* root1 = (const float*)d_in[14];
    const float* b1    = (const float*)d_in[15];
    const float* W2    = (const float*)d_in[16];
    const float* root2 = (const float*)d_in[17];
    const float* b2    = (const float*)d_in[18];
    const float* rele  = (const float*)d_in[19];
    (void)in_sizes; (void)n_in; (void)out_size; (void)ws_size;

    float* out    = (float*)d_out;            // [NN][OUTD]
    float* scores = out + (size_t)NN * OUTD;  // [2*NE]

    auto align = [](size_t x) { return (x + 255) & ~(size_t)255; };
    char* p = (char*)d_ws;
    auto alloc = [&](size_t bytes) -> char* {
        char* q = p; p += align(bytes); return q;
    };
    _Float16* emb16  = (_Float16*)alloc((size_t)NN * EMBD * 2);
    _Float16* xbufA  = (_Float16*)alloc((size_t)NN * 256 * 2);
    _Float16* xbufB  = (_Float16*)alloc((size_t)NN * 256 * 2);
    _Float16* out16  = xbufB;  // L2 output aliases xbufB (dead by then)
    _Float16* Bt0 = (_Float16*)alloc((size_t)256 * 2304 * 2);
    _Float16* Bt1 = (_Float16*)alloc((size_t)256 * 2304 * 2);
    _Float16* Bt2 = (_Float16*)alloc((size_t)256 * 2304 * 2);
    _Float16* BtP = (_Float16*)alloc((size_t)256 * EMBD * 2);
    _Float16* rel16 = (_Float16*)alloc((size_t)NR * OUTD * 2);
    int*   cnt    = (int*)alloc((size_t)NSEG * 4);
    int*   cursor = (int*)alloc((size_t)NSEG * 4);
    int*   offs   = (int*)alloc((size_t)(NSEG + 1032) * 4);  // padded for block staging
    int*   csr    = (int*)alloc((size_t)NE * 4);
    int*   bsums  = (int*)alloc(4096);
    int*   bpref  = (int*)alloc(4096);

    // --- CSR build ---
    hipMemsetAsync(cnt, 0, (size_t)NSEG * 4, stream);
    count_edges<<<(NE + 255) / 256, 256, 0, stream>>>(dst, rel, cnt, NE);
    const int NB = (NSEG + 511) / 512;
    scan1<<<NB, 512, 0, stream>>>(cnt, offs, bsums, NSEG);
    scan2<<<1, 1024, 0, stream>>>(bsums, bpref, NB);
    scan3<<<NB + 3, 512, 0, stream>>>(offs, cursor, bpref, NSEG, NE);  // includes pad
    scatter_edges<<<(NE + 255) / 256, 256, 0, stream>>>(dst, rel, src, cursor, csr, NE);

    // --- weight/embedding converts (tiled transpose, coalesced both sides) ---
    f32_to_f16_vec<<<2048, 256, 0, stream>>>(emb, emb16, (long)NN * EMBD / 4);
    f32_to_f16_vec<<<2, 256, 0, stream>>>(rele, rel16, (long)NR * OUTD / 4);
    build_bt<<<dim3(16, 8), 256, 0, stream>>>(Wp, EMBD, nullptr, BtP, PROJD, EMBD);
    build_bt<<<dim3(72, 8), 256, 0, stream>>>(root0, 256, W0, Bt0, HIDD, 2304);
    build_bt<<<dim3(72, 8), 256, 0, stream>>>(root1, 256, W1, Bt1, HIDD, 2304);
    build_bt<<<dim3(72, 7), 256, 0, stream>>>(root2, 256, W2, Bt2, OUTD, 2304);

    // --- projection: xbufA[nidx[i]] = fp16(emb[i] @ Wp + bp) ---
    // nidx is a permutation (arange) -> scatter covers every row; no memset needed.
    {
        dim3 g(2, (NN + 127) / 128);
        gemm16<true, false, true, false, false, true><<<g, 256, 0, stream>>>(
            emb16, EMBD, BtP, EMBD, bp, nidx, nullptr, xbufA, 256, nullptr, NN, 256, EMBD);
    }

    // --- fused RGCN layers ---
    const int GL = (NN + 63) / 64;
    rgcn_layer<true, false><<<GL, 512, 0, stream>>>(xbufA, Bt0, csr, offs, b0,
                                                    xbufB, 256, nullptr, HIDD);
    rgcn_layer<true, false><<<GL, 512, 0, stream>>>(xbufB, Bt1, csr, offs, b1,
                                                    xbufA, 256, nullptr, HIDD);
    rgcn_layer<false, true><<<GL, 512, 0, stream>>>(xbufA, Bt2, csr, offs, b2,
                                                    out16, OUTD, out, OUTD);

    // --- decoder ---
    decoder16<<<(2 * NE * 8 + 255) / 256, 256, 0, stream>>>(out16, rel16, src, dst, rel,
                                                            nsrc, ndst, nrel, scores);
}